// Round 1
// baseline (392.226 us; speedup 1.0000x reference)
//
#include <hip/hip_runtime.h>
#include <hip/hip_bf16.h>
#include <cstdint>
#include <cstddef>

// Problem: B=4, T=4096, D=1024, H=16, HD=64.
// qkv = x @ Wqkv  (16384x1024 @ 1024x3072)
// per-token head-attention: scores = q @ k^T / 8 (16x16), softmax over j, out = attn @ v
// final = out @ Wout (16384x1024 @ 1024x1024)

typedef __bf16 bf16x8 __attribute__((ext_vector_type(8)));
typedef __bf16 bf16x4 __attribute__((ext_vector_type(4)));
typedef float  f32x4  __attribute__((ext_vector_type(4)));

#define AS1 __attribute__((address_space(1)))
#define AS3 __attribute__((address_space(3)))

__device__ __forceinline__ void async_copy16(const void* g, void* l) {
    __builtin_amdgcn_global_load_lds((const AS1 void*)g, (AS3 void*)l, 16, 0, 0);
}

// ---------------- convert fp32 -> bf16 (vectorized) ----------------
__global__ __launch_bounds__(256) void cvt_bf16_kernel(const float4* __restrict__ in,
                                                       bf16x4* __restrict__ out, int n4) {
    int i = blockIdx.x * 256 + threadIdx.x;
    if (i >= n4) return;
    float4 v = in[i];
    bf16x4 o = { (__bf16)v.x, (__bf16)v.y, (__bf16)v.z, (__bf16)v.w };
    out[i] = o;
}

// ---------------- transpose + convert: in fp32 R x C -> out bf16 C x R ----------------
__global__ __launch_bounds__(256) void transpose_cvt_kernel(const float* __restrict__ in,
                                                            __bf16* __restrict__ out,
                                                            int R, int C) {
    __shared__ float tile[32][33];
    int c0 = blockIdx.x * 32, r0 = blockIdx.y * 32;
    int tx = threadIdx.x, ty = threadIdx.y; // 32 x 8
    #pragma unroll
    for (int i = 0; i < 32; i += 8)
        tile[ty + i][tx] = in[(size_t)(r0 + ty + i) * C + c0 + tx];
    __syncthreads();
    #pragma unroll
    for (int i = 0; i < 32; i += 8)
        out[(size_t)(c0 + ty + i) * R + r0 + tx] = (__bf16)tile[tx][ty + i];
}

// ---------------- bf16 GEMM, C = A @ Bt^T ----------------
// A: M x K bf16 row-major, Bt: N x K bf16 row-major (i.e. B transposed)
// 128x128 block tile, BK=32, 4 waves in 2x2, each wave 64x64 via 4x4 mfma_16x16x32.
template<int OUT_BF16>
__global__ __launch_bounds__(256) void gemm_bt(const __bf16* __restrict__ A,
                                               const __bf16* __restrict__ Bt,
                                               void* __restrict__ Cv,
                                               int N, int K) {
    __shared__ __bf16 As[128 * 32]; // [row][k] 64B rows, k-slots xor-swizzled
    __shared__ __bf16 Bs[128 * 32];

    const int tid  = threadIdx.x;
    const int wave = tid >> 6;
    const int lane = tid & 63;
    const int quad = lane >> 4;
    const int q16  = lane & 15;
    const int wr   = wave >> 1, wc = wave & 1;
    const int row0 = blockIdx.y * 128;
    const int col0 = blockIdx.x * 128;

    const __bf16* Ag = A  + (size_t)row0 * K;
    const __bf16* Bg = Bt + (size_t)col0 * K;

    // per-wave staging: 2 chunks of 1KB each for A and B tiles (8KB each)
    const int o0 = (wave * 2)     * 1024 + lane * 16; // byte offset in tile
    const int o1 = (wave * 2 + 1) * 1024 + lane * 16;
    const int r0 = o0 >> 6, r1 = o1 >> 6;             // tile row (64B rows)
    const int cb0 = ((o0 >> 4) & 3) ^ ((r0 >> 1) & 3); // logical k-group (swizzle)
    const int cb1 = ((o1 >> 4) & 3) ^ ((r1 >> 1) & 3);
    char* ldsA0 = (char*)As + (wave * 2)     * 1024;
    char* ldsA1 = (char*)As + (wave * 2 + 1) * 1024;
    char* ldsB0 = (char*)Bs + (wave * 2)     * 1024;
    char* ldsB1 = (char*)Bs + (wave * 2 + 1) * 1024;

    f32x4 acc[4][4] = {};

    for (int k0 = 0; k0 < K; k0 += 32) {
        async_copy16(Ag + (size_t)r0 * K + (k0 + cb0 * 8), ldsA0);
        async_copy16(Ag + (size_t)r1 * K + (k0 + cb1 * 8), ldsA1);
        async_copy16(Bg + (size_t)r0 * K + (k0 + cb0 * 8), ldsB0);
        async_copy16(Bg + (size_t)r1 * K + (k0 + cb1 * 8), ldsB1);
        __syncthreads(); // drains vmcnt(0): staged data visible

        bf16x8 af[4], bfr[4];
        #pragma unroll
        for (int mi = 0; mi < 4; ++mi) {
            int row = wr * 64 + mi * 16 + q16;
            int sl  = quad ^ ((row >> 1) & 3);
            af[mi] = *(const bf16x8*)((const char*)As + row * 64 + sl * 16);
        }
        #pragma unroll
        for (int ni = 0; ni < 4; ++ni) {
            int row = wc * 64 + ni * 16 + q16;
            int sl  = quad ^ ((row >> 1) & 3);
            bfr[ni] = *(const bf16x8*)((const char*)Bs + row * 64 + sl * 16);
        }
        #pragma unroll
        for (int mi = 0; mi < 4; ++mi)
            #pragma unroll
            for (int ni = 0; ni < 4; ++ni)
                acc[mi][ni] = __builtin_amdgcn_mfma_f32_16x16x32_bf16(af[mi], bfr[ni], acc[mi][ni], 0, 0, 0);
        __syncthreads(); // all reads done before next stage overwrites
    }

    // epilogue: D row = quad*4 + reg, col = q16 (per 16x16 tile)
    #pragma unroll
    for (int mi = 0; mi < 4; ++mi) {
        #pragma unroll
        for (int ni = 0; ni < 4; ++ni) {
            int col = col0 + wc * 64 + ni * 16 + q16;
            #pragma unroll
            for (int r = 0; r < 4; ++r) {
                int row = row0 + wr * 64 + mi * 16 + quad * 4 + r;
                if (OUT_BF16)
                    ((__bf16*)Cv)[(size_t)row * N + col] = (__bf16)acc[mi][ni][r];
                else
                    ((float*)Cv)[(size_t)row * N + col] = acc[mi][ni][r];
            }
        }
    }
}

// ---------------- per-token head attention ----------------
// qkv row layout per token: [3][16][64] (q,k,v). One block (256 thr) per token.
__global__ __launch_bounds__(256) void attn_kernel(const __bf16* __restrict__ qkv,
                                                   __bf16* __restrict__ ao) {
    __shared__ float sm[3 * 1040]; // [3][16][65] padded
    __shared__ float sa[16 * 16];
    const int tok = blockIdx.x;
    const int tid = threadIdx.x;
    const __bf16* base = qkv + (size_t)tok * 3072;

    for (int e = tid; e < 3072; e += 256) {
        float f = (float)base[e];
        int g = e >> 10, hh = (e >> 6) & 15, d = e & 63;
        sm[g * 1040 + hh * 65 + d] = f;
    }
    __syncthreads();

    const float* sq = sm;
    const float* sk = sm + 1040;
    const float* sv = sm + 2080;

    const int i = tid >> 4, j = tid & 15;
    float s = 0.f;
    #pragma unroll
    for (int d = 0; d < 64; ++d) s += sq[i * 65 + d] * sk[j * 65 + d];
    s *= 0.125f; // 1/sqrt(64)

    // softmax over j: rows are 16 consecutive lanes
    float m = s;
    #pragma unroll
    for (int off = 8; off; off >>= 1) m = fmaxf(m, __shfl_xor(m, off, 16));
    float e = __expf(s - m);
    float sum = e;
    #pragma unroll
    for (int off = 8; off; off >>= 1) sum += __shfl_xor(sum, off, 16);
    sa[i * 16 + j] = e / sum;
    __syncthreads();

    // out[i][d] = sum_j attn[i][j] * v[j][d]; thread covers d = j*4 .. j*4+3
    const int db = j;
    float a0 = 0.f, a1 = 0.f, a2 = 0.f, a3 = 0.f;
    #pragma unroll
    for (int jj = 0; jj < 16; ++jj) {
        float a = sa[i * 16 + jj];
        const float* vp = sv + jj * 65 + db * 4;
        a0 += a * vp[0]; a1 += a * vp[1]; a2 += a * vp[2]; a3 += a * vp[3];
    }
    bf16x4 o = { (__bf16)a0, (__bf16)a1, (__bf16)a2, (__bf16)a3 };
    *(bf16x4*)(ao + (size_t)tok * 1024 + i * 64 + db * 4) = o;
}

// ---------------- launch ----------------
extern "C" void kernel_launch(void* const* d_in, const int* in_sizes, int n_in,
                              void* d_out, int out_size, void* d_ws, size_t ws_size,
                              hipStream_t stream) {
    const float* x    = (const float*)d_in[0]; // 16384 x 1024
    const float* Wqkv = (const float*)d_in[1]; // 1024 x 3072
    const float* Wout = (const float*)d_in[2]; // 1024 x 1024
    float* out = (float*)d_out;                // 16384 x 1024

    char* ws = (char*)d_ws;
    const size_t MT = 16384;
    __bf16* xb    = (__bf16*)(ws);                                   // 32 MiB
    __bf16* wqkvT = (__bf16*)(ws + 33554432);                        // 6 MiB  (3072 x 1024)
    __bf16* woutT = (__bf16*)(ws + 33554432 + 6291456);              // 2 MiB  (1024 x 1024)
    __bf16* qkv   = (__bf16*)(ws + 33554432 + 6291456 + 2097152);    // 96 MiB (16384 x 3072)
    __bf16* ao    = (__bf16*)(ws + 33554432 + 6291456 + 2097152 + 100663296); // 32 MiB

    // convert x (16M elems, 4/thread)
    cvt_bf16_kernel<<<16384, 256, 0, stream>>>((const float4*)x, (bf16x4*)xb, 4194304);
    // transpose+convert weights to N x K bf16
    transpose_cvt_kernel<<<dim3(96, 32), dim3(32, 8), 0, stream>>>(Wqkv, wqkvT, 1024, 3072);
    transpose_cvt_kernel<<<dim3(32, 32), dim3(32, 8), 0, stream>>>(Wout, woutT, 1024, 1024);
    // GEMM1: qkv = xb @ WqkvT^T  (16384 x 3072)
    gemm_bt<1><<<dim3(24, 128), 256, 0, stream>>>(xb, wqkvT, (void*)qkv, 3072, 1024);
    // per-token attention
    attn_kernel<<<16384, 256, 0, stream>>>(qkv, ao);
    // GEMM2: out = ao @ WoutT^T (fp32 out)
    gemm_bt<0><<<dim3(8, 128), 256, 0, stream>>>(ao, woutT, (void*)out, 1024, 1024);
}

// Round 2
// 350.424 us; speedup vs baseline: 1.1193x; 1.1193x over previous
//
#include <hip/hip_runtime.h>
#include <hip/hip_bf16.h>
#include <cstdint>
#include <cstddef>

// Problem: B=4, T=4096, D=1024, H=16, HD=64.
// qkv = x @ Wqkv  (16384x1024 @ 1024x3072)
// per-token head-attention: scores[i,j] = q_i . k_j / 8 over heads i,j (16x16), softmax_j, out = P @ v
// final = out @ Wout (16384x1024 @ 1024x1024)

typedef __bf16 bf16x8 __attribute__((ext_vector_type(8)));
typedef __bf16 bf16x4 __attribute__((ext_vector_type(4)));
typedef float  f32x4  __attribute__((ext_vector_type(4)));

#define AS1 __attribute__((address_space(1)))
#define AS3 __attribute__((address_space(3)))

__device__ __forceinline__ void async_copy16(const void* g, void* l) {
    __builtin_amdgcn_global_load_lds((const AS1 void*)g, (AS3 void*)l, 16, 0, 0);
}

// ---------------- convert fp32 -> bf16 (vectorized) ----------------
__global__ __launch_bounds__(256) void cvt_bf16_kernel(const float4* __restrict__ in,
                                                       bf16x4* __restrict__ out, int n4) {
    int i = blockIdx.x * 256 + threadIdx.x;
    if (i >= n4) return;
    float4 v = in[i];
    bf16x4 o = { (__bf16)v.x, (__bf16)v.y, (__bf16)v.z, (__bf16)v.w };
    out[i] = o;
}

// ---------------- transpose + convert: in fp32 R x C -> out bf16 C x R ----------------
__global__ __launch_bounds__(256) void transpose_cvt_kernel(const float* __restrict__ in,
                                                            __bf16* __restrict__ out,
                                                            int R, int C) {
    __shared__ float tile[32][33];
    int c0 = blockIdx.x * 32, r0 = blockIdx.y * 32;
    int tx = threadIdx.x, ty = threadIdx.y; // 32 x 8
    #pragma unroll
    for (int i = 0; i < 32; i += 8)
        tile[ty + i][tx] = in[(size_t)(r0 + ty + i) * C + c0 + tx];
    __syncthreads();
    #pragma unroll
    for (int i = 0; i < 32; i += 8)
        out[(size_t)(c0 + ty + i) * R + r0 + tx] = (__bf16)tile[tx][ty + i];
}

// ---------------- bf16 GEMM, C = A @ Bt^T ----------------
// A: M x K bf16 row-major, Bt: N x K bf16 row-major (i.e. B transposed)
// 128x128 block tile, BK=32, 4 waves in 2x2, each wave 64x64 via 4x4 mfma_16x16x32.
template<int OUT_BF16>
__global__ __launch_bounds__(256) void gemm_bt(const __bf16* __restrict__ A,
                                               const __bf16* __restrict__ Bt,
                                               void* __restrict__ Cv,
                                               int N, int K) {
    __shared__ __bf16 As[128 * 32]; // [row][k] 64B rows, k-slots xor-swizzled
    __shared__ __bf16 Bs[128 * 32];

    const int tid  = threadIdx.x;
    const int wave = tid >> 6;
    const int lane = tid & 63;
    const int quad = lane >> 4;
    const int q16  = lane & 15;
    const int wr   = wave >> 1, wc = wave & 1;
    const int row0 = blockIdx.y * 128;
    const int col0 = blockIdx.x * 128;

    const __bf16* Ag = A  + (size_t)row0 * K;
    const __bf16* Bg = Bt + (size_t)col0 * K;

    // per-wave staging: 2 chunks of 1KB each for A and B tiles (8KB each)
    const int o0 = (wave * 2)     * 1024 + lane * 16; // byte offset in tile
    const int o1 = (wave * 2 + 1) * 1024 + lane * 16;
    const int r0 = o0 >> 6, r1 = o1 >> 6;             // tile row (64B rows)
    const int cb0 = ((o0 >> 4) & 3) ^ ((r0 >> 1) & 3); // logical k-group (swizzle)
    const int cb1 = ((o1 >> 4) & 3) ^ ((r1 >> 1) & 3);
    char* ldsA0 = (char*)As + (wave * 2)     * 1024;
    char* ldsA1 = (char*)As + (wave * 2 + 1) * 1024;
    char* ldsB0 = (char*)Bs + (wave * 2)     * 1024;
    char* ldsB1 = (char*)Bs + (wave * 2 + 1) * 1024;

    f32x4 acc[4][4] = {};

    for (int k0 = 0; k0 < K; k0 += 32) {
        async_copy16(Ag + (size_t)r0 * K + (k0 + cb0 * 8), ldsA0);
        async_copy16(Ag + (size_t)r1 * K + (k0 + cb1 * 8), ldsA1);
        async_copy16(Bg + (size_t)r0 * K + (k0 + cb0 * 8), ldsB0);
        async_copy16(Bg + (size_t)r1 * K + (k0 + cb1 * 8), ldsB1);
        __syncthreads(); // drains vmcnt(0): staged data visible

        bf16x8 af[4], bfr[4];
        #pragma unroll
        for (int mi = 0; mi < 4; ++mi) {
            int row = wr * 64 + mi * 16 + q16;
            int sl  = quad ^ ((row >> 1) & 3);
            af[mi] = *(const bf16x8*)((const char*)As + row * 64 + sl * 16);
        }
        #pragma unroll
        for (int ni = 0; ni < 4; ++ni) {
            int row = wc * 64 + ni * 16 + q16;
            int sl  = quad ^ ((row >> 1) & 3);
            bfr[ni] = *(const bf16x8*)((const char*)Bs + row * 64 + sl * 16);
        }
        #pragma unroll
        for (int mi = 0; mi < 4; ++mi)
            #pragma unroll
            for (int ni = 0; ni < 4; ++ni)
                acc[mi][ni] = __builtin_amdgcn_mfma_f32_16x16x32_bf16(af[mi], bfr[ni], acc[mi][ni], 0, 0, 0);
        __syncthreads(); // all reads done before next stage overwrites
    }

    // epilogue: D row = quad*4 + reg, col = q16 (per 16x16 tile)
    #pragma unroll
    for (int mi = 0; mi < 4; ++mi) {
        #pragma unroll
        for (int ni = 0; ni < 4; ++ni) {
            int col = col0 + wc * 64 + ni * 16 + q16;
            #pragma unroll
            for (int r = 0; r < 4; ++r) {
                int row = row0 + wr * 64 + mi * 16 + quad * 4 + r;
                if (OUT_BF16)
                    ((__bf16*)Cv)[(size_t)row * N + col] = (__bf16)acc[mi][ni][r];
                else
                    ((float*)Cv)[(size_t)row * N + col] = acc[mi][ni][r];
            }
        }
    }
}

// ---------------- per-token head attention, MFMA, one wave per token ----------------
// qkv row per token: [3][16][64] bf16 (q,k,v). No LDS, no barriers.
// S^T = K.Q^T via mfma_16x16x32 (C-layout: j=quad*4+r, i=q16); softmax over j;
// P^T C-layout == A-frag layout of P (K=16) after cross-quad dword shuffle;
// PV via K-padded mfma_16x16x32 (quads 2,3 contribute zeros).
__global__ __launch_bounds__(256) void attn_mfma_kernel(const __bf16* __restrict__ qkv,
                                                        __bf16* __restrict__ ao) {
    const int tok  = blockIdx.x * 4 + (threadIdx.x >> 6);
    const int lane = threadIdx.x & 63;
    const int quad = lane >> 4;
    const int q16  = lane & 15;

    const __bf16* base = qkv + (size_t)tok * 3072;
    const __bf16* vb   = base + 2048;

    // q/k fragments: lane reads row (q16) of the 16x64 matrix, 16B at d-offset quad*8 (+32)
    const bf16x8 qf0 = *(const bf16x8*)(base + q16 * 64 + quad * 8);
    const bf16x8 qf1 = *(const bf16x8*)(base + q16 * 64 + quad * 8 + 32);
    const bf16x8 kf0 = *(const bf16x8*)(base + 1024 + q16 * 64 + quad * 8);
    const bf16x8 kf1 = *(const bf16x8*)(base + 1024 + q16 * 64 + quad * 8 + 32);

    // S^T[j][i] = sum_d k[j][d] q[i][d]
    f32x4 st = {0.f, 0.f, 0.f, 0.f};
    st = __builtin_amdgcn_mfma_f32_16x16x32_bf16(kf0, qf0, st, 0, 0, 0);
    st = __builtin_amdgcn_mfma_f32_16x16x32_bf16(kf1, qf1, st, 0, 0, 0);

    // softmax over j (= 4 regs x 4 quads) for fixed i = q16
    float s0 = st[0] * 0.125f, s1 = st[1] * 0.125f, s2 = st[2] * 0.125f, s3 = st[3] * 0.125f;
    float m = fmaxf(fmaxf(s0, s1), fmaxf(s2, s3));
    m = fmaxf(m, __shfl_xor(m, 16));
    m = fmaxf(m, __shfl_xor(m, 32));
    float e0 = __expf(s0 - m), e1 = __expf(s1 - m), e2 = __expf(s2 - m), e3 = __expf(s3 - m);
    float sum = e0 + e1 + e2 + e3;
    sum += __shfl_xor(sum, 16);
    sum += __shfl_xor(sum, 32);
    const float inv = 1.f / sum;

    // pack P^T lane values (j = quad*4 + r, i = q16) into 2 dwords of bf16
    union { __bf16 h[2]; int i; } u01, u23;
    u01.h[0] = (__bf16)(e0 * inv); u01.h[1] = (__bf16)(e1 * inv);
    u23.h[0] = (__bf16)(e2 * inv); u23.h[1] = (__bf16)(e3 * inv);

    // A-frag of P for 16x16x32 (K padded to 32): lane needs P[q16][quad*8+idx]
    // = P^T[quad*8+idx][q16]; source lanes quad*32+q16 (idx 0..3) and +16 (idx 4..7).
    const int src0 = quad * 32 + q16;
    const int src1 = src0 + 16;
    union { int i[4]; bf16x8 v; } af;
    af.i[0] = __shfl(u01.i, src0);
    af.i[1] = __shfl(u23.i, src0);
    af.i[2] = __shfl(u01.i, src1);
    af.i[3] = __shfl(u23.i, src1);
    if (quad >= 2) { af.i[0] = 0; af.i[1] = 0; af.i[2] = 0; af.i[3] = 0; }

    // PV: out[i][d] = sum_j P[i][j] v[j][d], 4 d-chunks of 16.
    __bf16* outp = ao + (size_t)tok * 1024;
    #pragma unroll
    for (int c = 0; c < 4; ++c) {
        const int d0 = c * 16;
        bf16x8 bf = {};
        if (quad < 2) {
            #pragma unroll
            for (int idx = 0; idx < 8; ++idx)
                bf[idx] = vb[(quad * 8 + idx) * 64 + d0 + q16];
        }
        f32x4 acc = {0.f, 0.f, 0.f, 0.f};
        acc = __builtin_amdgcn_mfma_f32_16x16x32_bf16(af.v, bf, acc, 0, 0, 0);
        // D C-layout: lane holds out[i = quad*4 + r][d0 + q16]
        #pragma unroll
        for (int r = 0; r < 4; ++r)
            outp[(quad * 4 + r) * 64 + d0 + q16] = (__bf16)acc[r];
    }
}

// ---------------- launch ----------------
extern "C" void kernel_launch(void* const* d_in, const int* in_sizes, int n_in,
                              void* d_out, int out_size, void* d_ws, size_t ws_size,
                              hipStream_t stream) {
    const float* x    = (const float*)d_in[0]; // 16384 x 1024
    const float* Wqkv = (const float*)d_in[1]; // 1024 x 3072
    const float* Wout = (const float*)d_in[2]; // 1024 x 1024
    float* out = (float*)d_out;                // 16384 x 1024

    char* ws = (char*)d_ws;
    __bf16* xb    = (__bf16*)(ws);                                   // 32 MiB
    __bf16* wqkvT = (__bf16*)(ws + 33554432);                        // 6 MiB  (3072 x 1024)
    __bf16* woutT = (__bf16*)(ws + 33554432 + 6291456);              // 2 MiB  (1024 x 1024)
    __bf16* qkv   = (__bf16*)(ws + 33554432 + 6291456 + 2097152);    // 96 MiB (16384 x 3072)
    __bf16* ao    = (__bf16*)(ws + 33554432 + 6291456 + 2097152 + 100663296); // 32 MiB

    // convert x (16M elems, 4/thread)
    cvt_bf16_kernel<<<16384, 256, 0, stream>>>((const float4*)x, (bf16x4*)xb, 4194304);
    // transpose+convert weights to N x K bf16
    transpose_cvt_kernel<<<dim3(96, 32), dim3(32, 8), 0, stream>>>(Wqkv, wqkvT, 1024, 3072);
    transpose_cvt_kernel<<<dim3(32, 32), dim3(32, 8), 0, stream>>>(Wout, woutT, 1024, 1024);
    // GEMM1: qkv = xb @ WqkvT^T  (16384 x 3072)
    gemm_bt<1><<<dim3(24, 128), 256, 0, stream>>>(xb, wqkvT, (void*)qkv, 3072, 1024);
    // per-token attention (one wave per token, 4 waves/block)
    attn_mfma_kernel<<<4096, 256, 0, stream>>>(qkv, ao);
    // GEMM2: out = ao @ WoutT^T (fp32 out)
    gemm_bt<0><<<dim3(8, 128), 256, 0, stream>>>(ao, woutT, (void*)out, 1024, 1024);
}

// Round 3
// 348.830 us; speedup vs baseline: 1.1244x; 1.0046x over previous
//
#include <hip/hip_runtime.h>
#include <hip/hip_bf16.h>
#include <cstdint>
#include <cstddef>

// Problem: B=4, T=4096, D=1024, H=16, HD=64.
// qkv = x @ Wqkv  (16384x1024 @ 1024x3072)
// per-token head-attention: scores[i,j] = q_i . k_j / 8 over heads i,j (16x16), softmax_j, out = P @ v
// final = out @ Wout (16384x1024 @ 1024x1024)

typedef __bf16 bf16x8 __attribute__((ext_vector_type(8)));
typedef __bf16 bf16x4 __attribute__((ext_vector_type(4)));
typedef float  f32x4  __attribute__((ext_vector_type(4)));

#define AS1 __attribute__((address_space(1)))
#define AS3 __attribute__((address_space(3)))

__device__ __forceinline__ void async_copy16(const void* g, void* l) {
    __builtin_amdgcn_global_load_lds((const AS1 void*)g, (AS3 void*)l, 16, 0, 0);
}

// ---------------- convert fp32 -> bf16 (vectorized) ----------------
__global__ __launch_bounds__(256) void cvt_bf16_kernel(const float4* __restrict__ in,
                                                       bf16x4* __restrict__ out, int n4) {
    int i = blockIdx.x * 256 + threadIdx.x;
    if (i >= n4) return;
    float4 v = in[i];
    bf16x4 o = { (__bf16)v.x, (__bf16)v.y, (__bf16)v.z, (__bf16)v.w };
    out[i] = o;
}

// ---------------- transpose + convert: in fp32 R x C -> out bf16 C x R ----------------
__global__ __launch_bounds__(256) void transpose_cvt_kernel(const float* __restrict__ in,
                                                            __bf16* __restrict__ out,
                                                            int R, int C) {
    __shared__ float tile[32][33];
    int c0 = blockIdx.x * 32, r0 = blockIdx.y * 32;
    int tx = threadIdx.x, ty = threadIdx.y; // 32 x 8
    #pragma unroll
    for (int i = 0; i < 32; i += 8)
        tile[ty + i][tx] = in[(size_t)(r0 + ty + i) * C + c0 + tx];
    __syncthreads();
    #pragma unroll
    for (int i = 0; i < 32; i += 8)
        out[(size_t)(c0 + ty + i) * R + r0 + tx] = (__bf16)tile[tx][ty + i];
}

// ---------------- bf16 GEMM, C = A @ Bt^T ----------------
// A: M x K bf16 row-major, Bt: N x K bf16 row-major (i.e. B transposed)
// 128x128 block tile, BK=32, 4 waves in 2x2, each wave 64x64 via 4x4 mfma_16x16x32.
template<int OUT_BF16>
__global__ __launch_bounds__(256) void gemm_bt(const __bf16* __restrict__ A,
                                               const __bf16* __restrict__ Bt,
                                               void* __restrict__ Cv,
                                               int N, int K) {
    __shared__ __bf16 As[128 * 32]; // [row][k] 64B rows, k-slots xor-swizzled
    __shared__ __bf16 Bs[128 * 32];

    const int tid  = threadIdx.x;
    const int wave = tid >> 6;
    const int lane = tid & 63;
    const int quad = lane >> 4;
    const int q16  = lane & 15;
    const int wr   = wave >> 1, wc = wave & 1;
    const int row0 = blockIdx.y * 128;
    const int col0 = blockIdx.x * 128;

    const __bf16* Ag = A  + (size_t)row0 * K;
    const __bf16* Bg = Bt + (size_t)col0 * K;

    // per-wave staging: 2 chunks of 1KB each for A and B tiles (8KB each)
    const int o0 = (wave * 2)     * 1024 + lane * 16; // byte offset in tile
    const int o1 = (wave * 2 + 1) * 1024 + lane * 16;
    const int r0 = o0 >> 6, r1 = o1 >> 6;             // tile row (64B rows)
    const int cb0 = ((o0 >> 4) & 3) ^ ((r0 >> 1) & 3); // logical k-group (swizzle)
    const int cb1 = ((o1 >> 4) & 3) ^ ((r1 >> 1) & 3);
    char* ldsA0 = (char*)As + (wave * 2)     * 1024;
    char* ldsA1 = (char*)As + (wave * 2 + 1) * 1024;
    char* ldsB0 = (char*)Bs + (wave * 2)     * 1024;
    char* ldsB1 = (char*)Bs + (wave * 2 + 1) * 1024;

    f32x4 acc[4][4] = {};

    for (int k0 = 0; k0 < K; k0 += 32) {
        async_copy16(Ag + (size_t)r0 * K + (k0 + cb0 * 8), ldsA0);
        async_copy16(Ag + (size_t)r1 * K + (k0 + cb1 * 8), ldsA1);
        async_copy16(Bg + (size_t)r0 * K + (k0 + cb0 * 8), ldsB0);
        async_copy16(Bg + (size_t)r1 * K + (k0 + cb1 * 8), ldsB1);
        __syncthreads(); // drains vmcnt(0): staged data visible

        bf16x8 af[4], bfr[4];
        #pragma unroll
        for (int mi = 0; mi < 4; ++mi) {
            int row = wr * 64 + mi * 16 + q16;
            int sl  = quad ^ ((row >> 1) & 3);
            af[mi] = *(const bf16x8*)((const char*)As + row * 64 + sl * 16);
        }
        #pragma unroll
        for (int ni = 0; ni < 4; ++ni) {
            int row = wc * 64 + ni * 16 + q16;
            int sl  = quad ^ ((row >> 1) & 3);
            bfr[ni] = *(const bf16x8*)((const char*)Bs + row * 64 + sl * 16);
        }
        #pragma unroll
        for (int mi = 0; mi < 4; ++mi)
            #pragma unroll
            for (int ni = 0; ni < 4; ++ni)
                acc[mi][ni] = __builtin_amdgcn_mfma_f32_16x16x32_bf16(af[mi], bfr[ni], acc[mi][ni], 0, 0, 0);
        __syncthreads(); // all reads done before next stage overwrites
    }

    // epilogue: D row = quad*4 + reg, col = q16 (per 16x16 tile)
    #pragma unroll
    for (int mi = 0; mi < 4; ++mi) {
        #pragma unroll
        for (int ni = 0; ni < 4; ++ni) {
            int col = col0 + wc * 64 + ni * 16 + q16;
            #pragma unroll
            for (int r = 0; r < 4; ++r) {
                int row = row0 + wr * 64 + mi * 16 + quad * 4 + r;
                if (OUT_BF16)
                    ((__bf16*)Cv)[(size_t)row * N + col] = (__bf16)acc[mi][ni][r];
                else
                    ((float*)Cv)[(size_t)row * N + col] = acc[mi][ni][r];
            }
        }
    }
}

// ---------------- per-token head attention, MFMA, one wave per token ----------------
// qkv row per token: [3][16][64] bf16 (q,k,v).
// S^T = K.Q^T via mfma_16x16x32 (C-layout: j=quad*4+r, i=q16); softmax over j;
// P^T C-layout -> A-frag of P (K padded to 32) via cross-quad dword shuffle;
// V staged in wave-private LDS (coalesced b128 in, swizzled; ds_read_u16 B-frag out).
__global__ __launch_bounds__(256) void attn_mfma_kernel(const __bf16* __restrict__ qkv,
                                                        __bf16* __restrict__ ao) {
    // per-wave V tile: 16 rows x 72 elems (pad) = 2304 B; 4 waves/block
    __shared__ __bf16 vsh[4][16 * 72];

    const int w    = threadIdx.x >> 6;
    const int tok  = blockIdx.x * 4 + w;
    const int lane = threadIdx.x & 63;
    const int quad = lane >> 4;
    const int q16  = lane & 15;

    const __bf16* base = qkv + (size_t)tok * 3072;
    const __bf16* vb   = base + 2048;
    __bf16* vsw = vsh[w];

    // stage V: lane loads 32B (row j = lane>>2, d-group dp = lane&3), swizzled 16B slots
    {
        const int j  = lane >> 2;
        const int dp = lane & 3;
        const int sw = dp ^ (j >> 2);
        const bf16x8 v0 = *(const bf16x8*)(vb + lane * 16);
        const bf16x8 v1 = *(const bf16x8*)(vb + lane * 16 + 8);
        *(bf16x8*)(vsw + j * 72 + sw * 16)     = v0;
        *(bf16x8*)(vsw + j * 72 + sw * 16 + 8) = v1;
    }

    // q/k fragments: lane reads row (q16) of the 16x64 matrix, 16B at d-offset quad*8 (+32)
    const bf16x8 qf0 = *(const bf16x8*)(base + q16 * 64 + quad * 8);
    const bf16x8 qf1 = *(const bf16x8*)(base + q16 * 64 + quad * 8 + 32);
    const bf16x8 kf0 = *(const bf16x8*)(base + 1024 + q16 * 64 + quad * 8);
    const bf16x8 kf1 = *(const bf16x8*)(base + 1024 + q16 * 64 + quad * 8 + 32);

    // S^T[j][i] = sum_d k[j][d] q[i][d]
    f32x4 st = {0.f, 0.f, 0.f, 0.f};
    st = __builtin_amdgcn_mfma_f32_16x16x32_bf16(kf0, qf0, st, 0, 0, 0);
    st = __builtin_amdgcn_mfma_f32_16x16x32_bf16(kf1, qf1, st, 0, 0, 0);

    // softmax over j (= 4 regs x 4 quads) for fixed i = q16
    float s0 = st[0] * 0.125f, s1 = st[1] * 0.125f, s2 = st[2] * 0.125f, s3 = st[3] * 0.125f;
    float m = fmaxf(fmaxf(s0, s1), fmaxf(s2, s3));
    m = fmaxf(m, __shfl_xor(m, 16));
    m = fmaxf(m, __shfl_xor(m, 32));
    float e0 = __expf(s0 - m), e1 = __expf(s1 - m), e2 = __expf(s2 - m), e3 = __expf(s3 - m);
    float sum = e0 + e1 + e2 + e3;
    sum += __shfl_xor(sum, 16);
    sum += __shfl_xor(sum, 32);
    const float inv = 1.f / sum;

    // pack P^T lane values (j = quad*4 + r, i = q16) into 2 dwords of bf16
    union { __bf16 h[2]; int i; } u01, u23;
    u01.h[0] = (__bf16)(e0 * inv); u01.h[1] = (__bf16)(e1 * inv);
    u23.h[0] = (__bf16)(e2 * inv); u23.h[1] = (__bf16)(e3 * inv);

    // A-frag of P for 16x16x32 (K padded to 32): lane needs P[q16][quad*8+idx]
    // = P^T[quad*8+idx][q16]; source lanes quad*32+q16 (idx 0..3) and +16 (idx 4..7).
    const int src0 = quad * 32 + q16;
    const int src1 = src0 + 16;
    union { int i[4]; bf16x8 v; } af;
    af.i[0] = __shfl(u01.i, src0);
    af.i[1] = __shfl(u23.i, src0);
    af.i[2] = __shfl(u01.i, src1);
    af.i[3] = __shfl(u23.i, src1);
    if (quad >= 2) { af.i[0] = 0; af.i[1] = 0; af.i[2] = 0; af.i[3] = 0; }

    __syncthreads(); // V staged (also orders ds_write -> ds_read)

    // PV: out[i][d] = sum_j P[i][j] v[j][d], 4 d-chunks of 16.
    __bf16* outp = ao + (size_t)tok * 1024;
    #pragma unroll
    for (int c = 0; c < 4; ++c) {
        const int d0 = c * 16;
        bf16x8 bfv = {};
        if (quad < 2) {
            #pragma unroll
            for (int idx = 0; idx < 8; ++idx) {
                const int row = quad * 8 + idx;
                bfv[idx] = vsw[row * 72 + ((c ^ (row >> 2)) << 4) + q16];
            }
        }
        f32x4 acc = {0.f, 0.f, 0.f, 0.f};
        acc = __builtin_amdgcn_mfma_f32_16x16x32_bf16(af.v, bfv, acc, 0, 0, 0);
        // D C-layout: lane holds out[i = quad*4 + r][d0 + q16]
        #pragma unroll
        for (int r = 0; r < 4; ++r)
            outp[(quad * 4 + r) * 64 + d0 + q16] = (__bf16)acc[r];
    }
}

// ---------------- launch ----------------
extern "C" void kernel_launch(void* const* d_in, const int* in_sizes, int n_in,
                              void* d_out, int out_size, void* d_ws, size_t ws_size,
                              hipStream_t stream) {
    const float* x    = (const float*)d_in[0]; // 16384 x 1024
    const float* Wqkv = (const float*)d_in[1]; // 1024 x 3072
    const float* Wout = (const float*)d_in[2]; // 1024 x 1024
    float* out = (float*)d_out;                // 16384 x 1024

    char* ws = (char*)d_ws;
    __bf16* xb    = (__bf16*)(ws);                                   // 32 MiB
    __bf16* wqkvT = (__bf16*)(ws + 33554432);                        // 6 MiB  (3072 x 1024)
    __bf16* woutT = (__bf16*)(ws + 33554432 + 6291456);              // 2 MiB  (1024 x 1024)
    __bf16* qkv   = (__bf16*)(ws + 33554432 + 6291456 + 2097152);    // 96 MiB (16384 x 3072)
    __bf16* ao    = (__bf16*)(ws + 33554432 + 6291456 + 2097152 + 100663296); // 32 MiB

    // convert x (16M elems, 4/thread)
    cvt_bf16_kernel<<<16384, 256, 0, stream>>>((const float4*)x, (bf16x4*)xb, 4194304);
    // transpose+convert weights to N x K bf16
    transpose_cvt_kernel<<<dim3(96, 32), dim3(32, 8), 0, stream>>>(Wqkv, wqkvT, 1024, 3072);
    transpose_cvt_kernel<<<dim3(32, 32), dim3(32, 8), 0, stream>>>(Wout, woutT, 1024, 1024);
    // GEMM1: qkv = xb @ WqkvT^T  (16384 x 3072)
    gemm_bt<1><<<dim3(24, 128), 256, 0, stream>>>(xb, wqkvT, (void*)qkv, 3072, 1024);
    // per-token attention (one wave per token, 4 waves/block)
    attn_mfma_kernel<<<4096, 256, 0, stream>>>(qkv, ao);
    // GEMM2: out = ao @ WoutT^T (fp32 out)
    gemm_bt<0><<<dim3(8, 128), 256, 0, stream>>>(ao, woutT, (void*)out, 1024, 1024);
}